// Round 9
// baseline (81.518 us; speedup 1.0000x reference)
//
#include <hip/hip_runtime.h>
#include <hip/hip_bf16.h>

#define T_LEN 2048
#define D_DIM 128
#define K_DIM 2048
#define M_DIM 8192
#define LOOKUP 101
#define HWIN 50

typedef __attribute__((ext_vector_type(8))) short short8;
typedef __attribute__((ext_vector_type(4))) float f32x4;

static __device__ __forceinline__ unsigned int f2bf(float f) {
  unsigned int u = __float_as_uint(f);
  return (u + 0x7fffu + ((u >> 16) & 1u)) >> 16;  // RNE bf16 bits
}

static __device__ __forceinline__ short8 pack8(float4 lo, float4 hi) {
  uint4 u;
  u.x = f2bf(lo.x) | (f2bf(lo.y) << 16);
  u.y = f2bf(lo.z) | (f2bf(lo.w) << 16);
  u.z = f2bf(hi.x) | (f2bf(hi.y) << 16);
  u.w = f2bf(hi.z) | (f2bf(hi.w) << 16);
  return *(short8*)&u;
}

// ---- Kernel 1: W [2048][128] f32 -> Bp fragment-packed bf16 (512 KB) ----
__global__ __launch_bounds__(256) void k_pack(const float* __restrict__ W,
                                              unsigned short* __restrict__ Bp) {
  __shared__ float sw[32][132];
  const int ks = blockIdx.x;  // 0..63
  const int t = threadIdx.x;
  const float* src = W + (size_t)ks * 32 * D_DIM;
#pragma unroll
  for (int j = 0; j < 4; ++j) {
    int idx = t + j * 256;
    int row = idx >> 5, c4 = idx & 31;
    float4 v = *(const float4*)(src + row * D_DIM + c4 * 4);
    *(float4*)&sw[row][c4 * 4] = v;
  }
  __syncthreads();
#pragma unroll
  for (int e = 0; e < 2; ++e) {
    int f = t * 2 + e;
    int ct = f >> 6, l = f & 63;
    int kr = (l >> 4) * 8, col = ct * 16 + (l & 15);
    uint4 o;
    o.x = f2bf(sw[kr + 0][col]) | (f2bf(sw[kr + 1][col]) << 16);
    o.y = f2bf(sw[kr + 2][col]) | (f2bf(sw[kr + 3][col]) << 16);
    o.z = f2bf(sw[kr + 4][col]) | (f2bf(sw[kr + 5][col]) << 16);
    o.w = f2bf(sw[kr + 6][col]) | (f2bf(sw[kr + 7][col]) << 16);
    *(uint4*)(Bp + (((size_t)(ks * 8 + ct) << 6) + l) * 8) = o;
  }
}

// ---- Kernel 2: 32 rows/wave register-direct GEMM, K-split-8, k-phase stagger ----
// REP=2 DIAGNOSTIC: recomputes the identical result twice (idempotent, deterministic)
// so the dispatch rises above the harness fillBuffer dispatches in the profile top-5
// and we finally get steady-state counters. Per-iter time = dur/2.
__global__ __launch_bounds__(512, 2) void k_gemm(const float* __restrict__ X,
                                                 const unsigned short* __restrict__ Bp,
                                                 const float* __restrict__ bias,
                                                 unsigned short* __restrict__ Pn) {
  __shared__ __align__(16) unsigned char Pw[4 * 16384];  // 64 KiB: 4 partial buffers
  const int tid = threadIdx.x;
  const int lane = tid & 63;
  const int wv = tid >> 6;
  const int r0 = blockIdx.x * 32;
  const int l15 = lane & 15;
  const int kg = lane >> 4;
  const int bph = blockIdx.x & 7;  // per-block k-phase stagger

  const float* xb0 = X + (size_t)(r0 + l15) * K_DIM + wv * 256 + kg * 8;
  const float* xb1 = xb0 + (size_t)16 * K_DIM;

#pragma unroll 1
  for (int rep = 0; rep < 2; ++rep) {
    f32x4 acc[2][8];
#pragma unroll
    for (int g = 0; g < 2; ++g)
#pragma unroll
      for (int i = 0; i < 8; ++i) acc[g][i] = (f32x4){0.f, 0.f, 0.f, 0.f};

    float4 xc[2][2], xn[2][2];
    short8 wc[8], wn[8];

    {
      int sp = bph;
      xc[0][0] = *(const float4*)(xb0 + sp * 32);
      xc[0][1] = *(const float4*)(xb0 + sp * 32 + 4);
      xc[1][0] = *(const float4*)(xb1 + sp * 32);
      xc[1][1] = *(const float4*)(xb1 + sp * 32 + 4);
#pragma unroll
      for (int ct = 0; ct < 8; ++ct)
        wc[ct] = *(const short8*)(Bp + (((size_t)(wv * 8 + sp) * 8 + ct) * 64 + lane) * 8);
    }

#pragma unroll
    for (int s = 0; s < 8; ++s) {
      if (s < 7) {
        int spn = (s + 1 + bph) & 7;
        xn[0][0] = *(const float4*)(xb0 + spn * 32);
        xn[0][1] = *(const float4*)(xb0 + spn * 32 + 4);
        xn[1][0] = *(const float4*)(xb1 + spn * 32);
        xn[1][1] = *(const float4*)(xb1 + spn * 32 + 4);
#pragma unroll
        for (int ct = 0; ct < 8; ++ct)
          wn[ct] = *(const short8*)(Bp + (((size_t)(wv * 8 + spn) * 8 + ct) * 64 + lane) * 8);
      }
      short8 xf0 = pack8(xc[0][0], xc[0][1]);
      short8 xf1 = pack8(xc[1][0], xc[1][1]);
#pragma unroll
      for (int ct = 0; ct < 8; ++ct)
        acc[0][ct] = __builtin_amdgcn_mfma_f32_16x16x32_bf16(wc[ct], xf0, acc[0][ct], 0, 0, 0);
#pragma unroll
      for (int ct = 0; ct < 8; ++ct)
        acc[1][ct] = __builtin_amdgcn_mfma_f32_16x16x32_bf16(wc[ct], xf1, acc[1][ct], 0, 0, 0);
      if (s < 7) {
        xc[0][0] = xn[0][0]; xc[0][1] = xn[0][1];
        xc[1][0] = xn[1][0]; xc[1][1] = xn[1][1];
#pragma unroll
        for (int ct = 0; ct < 8; ++ct) wc[ct] = wn[ct];
      }
    }

    // ---- two-stage reduce over the 8 K-slices ----
    if (wv >= 4) {
      unsigned char* pb = Pw + (wv - 4) * 16384;
#pragma unroll
      for (int rg = 0; rg < 2; ++rg)
#pragma unroll
        for (int ct = 0; ct < 8; ++ct) {
          int byte = (rg * 16 + l15) * 512 + ((ct * 64 + kg * 16) ^ ((l15 & 7) << 4));
          *(float4*)(pb + byte) =
              make_float4(acc[rg][ct][0], acc[rg][ct][1], acc[rg][ct][2], acc[rg][ct][3]);
        }
    }
    __syncthreads();
    if (wv < 4) {
      unsigned char* pb = Pw + wv * 16384;
#pragma unroll
      for (int rg = 0; rg < 2; ++rg)
#pragma unroll
        for (int ct = 0; ct < 8; ++ct) {
          int byte = (rg * 16 + l15) * 512 + ((ct * 64 + kg * 16) ^ ((l15 & 7) << 4));
          float4 v = *(float4*)(pb + byte);
          v.x += acc[rg][ct][0]; v.y += acc[rg][ct][1];
          v.z += acc[rg][ct][2]; v.w += acc[rg][ct][3];
          *(float4*)(pb + byte) = v;
        }
    }
    __syncthreads();

    // stage 2: reduce 4 buffers + bias + row-normalize + store bf16
    const int row = tid >> 4;   // 0..31
    const int c8 = tid & 15;    // 8 cols each
    float tot[8];
#pragma unroll
    for (int i = 0; i < 8; ++i) tot[i] = 0.f;
#pragma unroll
    for (int q = 0; q < 4; ++q)
#pragma unroll
      for (int h = 0; h < 2; ++h) {
        int byte = q * 16384 + row * 512 + ((c8 * 32 + h * 16) ^ ((row & 7) << 4));
        float4 v = *(const float4*)(Pw + byte);
        tot[h * 4 + 0] += v.x; tot[h * 4 + 1] += v.y;
        tot[h * 4 + 2] += v.z; tot[h * 4 + 3] += v.w;
      }
    float4 bv0 = *(const float4*)(bias + c8 * 8);
    float4 bv1 = *(const float4*)(bias + c8 * 8 + 4);
    tot[0] += bv0.x; tot[1] += bv0.y; tot[2] += bv0.z; tot[3] += bv0.w;
    tot[4] += bv1.x; tot[5] += bv1.y; tot[6] += bv1.z; tot[7] += bv1.w;
    float ss = 0.f;
#pragma unroll
    for (int i = 0; i < 8; ++i) ss += tot[i] * tot[i];
    ss += __shfl_xor(ss, 1);
    ss += __shfl_xor(ss, 2);
    ss += __shfl_xor(ss, 4);
    ss += __shfl_xor(ss, 8);
    float sc = 1.0f / fmaxf(sqrtf(ss), 1e-12f);
    uint4 o;
    o.x = f2bf(tot[0] * sc) | (f2bf(tot[1] * sc) << 16);
    o.y = f2bf(tot[2] * sc) | (f2bf(tot[3] * sc) << 16);
    o.z = f2bf(tot[4] * sc) | (f2bf(tot[5] * sc) << 16);
    o.w = f2bf(tot[6] * sc) | (f2bf(tot[7] * sc) << 16);
    *(uint4*)(Pn + (size_t)(r0 + row) * D_DIM + c8 * 8) = o;
    __syncthreads();  // Pw reused next rep
  }
}

// ---------------- Kernel 3: banded similarity via MFMA ----------------
#define SROWS 144

__global__ __launch_bounds__(256) void k_sim(const unsigned short* __restrict__ Pn,
                                             float* __restrict__ out) {
  __shared__ unsigned short sm[SROWS * D_DIM];  // 36 KiB, XOR-swizzled 8-short groups
  const int bb = blockIdx.x >> 6;
  const int tb = blockIdx.x & 63;
  const int t0 = tb * 32;
  const int tid = threadIdx.x;

  for (int idx = tid; idx < SROWS * 16; idx += 256) {
    int i = idx >> 4, seg = idx & 15;
    int t = t0 - HWIN + i;
    uint4 val = make_uint4(0u, 0u, 0u, 0u);
    if (t >= 0 && t < T_LEN)
      val = *(const uint4*)(Pn + ((size_t)bb * T_LEN + t) * D_DIM + seg * 8);
    *(uint4*)&sm[i * D_DIM + ((seg ^ (i & 7)) << 3)] = val;
  }
  __syncthreads();

  const int lane = tid & 63;
  const int wv = tid >> 6;
  const int l15 = lane & 15;
  const int kg = lane >> 4;
  const int rt = wv >> 1;
  const int itp = wv & 1;

  short8 af[4];
  const int ia = HWIN + rt * 16 + l15;
#pragma unroll
  for (int ks = 0; ks < 4; ++ks) {
    int g = ks * 4 + kg;
    af[ks] = *(const short8*)&sm[ia * D_DIM + ((g ^ (ia & 7)) << 3)];
  }

  for (int it = itp; it < 9; it += 2) {
    f32x4 acc = (f32x4){0.f, 0.f, 0.f, 0.f};
    const int ib = it * 16 + l15;
#pragma unroll
    for (int ks = 0; ks < 4; ++ks) {
      int g = ks * 4 + kg;
      short8 bf = *(const short8*)&sm[ib * D_DIM + ((g ^ (ib & 7)) << 3)];
      acc = __builtin_amdgcn_mfma_f32_16x16x32_bf16(af[ks], bf, acc, 0, 0, 0);
    }
#pragma unroll
    for (int j = 0; j < 4; ++j) {
      int r = rt * 16 + kg * 4 + j;
      int w = ib - r;
      if (w >= 0 && w <= 100)
        out[((size_t)bb * T_LEN + t0 + r) * LOOKUP + w] = acc[j];
    }
  }
}

extern "C" void kernel_launch(void* const* d_in, const int* in_sizes, int n_in,
                              void* d_out, int out_size, void* d_ws, size_t ws_size,
                              hipStream_t stream) {
  (void)in_sizes; (void)n_in; (void)out_size; (void)ws_size;
  const float* x = (const float*)d_in[0];
  const float* W = (const float*)d_in[1];
  const float* b = (const float*)d_in[2];
  float* out = (float*)d_out;
  unsigned short* Bp = (unsigned short*)d_ws;            // 512 KiB fragment-packed W
  unsigned short* Pn = Bp + (size_t)D_DIM * K_DIM;       // 8192*128 bf16 = 2 MiB

  k_pack<<<64, 256, 0, stream>>>(W, Bp);
  k_gemm<<<M_DIM / 32, 512, 0, stream>>>(x, Bp, b, Pn);
  k_sim<<<4 * (T_LEN / 32), 256, 0, stream>>>(Pn, out);
}

// Round 10
// 40.049 us; speedup vs baseline: 2.0354x; 2.0354x over previous
//
#include <hip/hip_runtime.h>
#include <hip/hip_bf16.h>

#define T_LEN 2048
#define D_DIM 128
#define K_DIM 2048
#define M_DIM 8192
#define LOOKUP 101
#define HWIN 50

typedef __attribute__((ext_vector_type(8))) short short8;
typedef __attribute__((ext_vector_type(4))) float f32x4;

static __device__ __forceinline__ unsigned int f2bf(float f) {
  unsigned int u = __float_as_uint(f);
  return (u + 0x7fffu + ((u >> 16) & 1u)) >> 16;  // RNE bf16 bits
}

static __device__ __forceinline__ short8 pack8(float4 lo, float4 hi) {
  uint4 u;
  u.x = f2bf(lo.x) | (f2bf(lo.y) << 16);
  u.y = f2bf(lo.z) | (f2bf(lo.w) << 16);
  u.z = f2bf(hi.x) | (f2bf(hi.y) << 16);
  u.w = f2bf(hi.z) | (f2bf(hi.w) << 16);
  return *(short8*)&u;
}

typedef __attribute__((address_space(3))) unsigned char lds_uchar;
typedef const __attribute__((address_space(1))) unsigned char g_uchar;
static __device__ __forceinline__ void gll16(const void* g, void* l) {
  __builtin_amdgcn_global_load_lds((g_uchar*)g, (lds_uchar*)l, 16, 0, 0);
}

// ---- Kernel 1: W [2048][128] f32 -> Bp fragment-packed bf16 (512 KB) ----
// Bp granule (ksg, ct, lane) 16B = bf16 of W[ksg*32 + (lane>>4)*8 + j][ct*16 + (lane&15)], j=0..7
__global__ __launch_bounds__(256) void k_pack(const float* __restrict__ W,
                                              unsigned short* __restrict__ Bp) {
  __shared__ float sw[32][132];
  const int ks = blockIdx.x;  // 0..63
  const int t = threadIdx.x;
  const float* src = W + (size_t)ks * 32 * D_DIM;
#pragma unroll
  for (int j = 0; j < 4; ++j) {
    int idx = t + j * 256;
    int row = idx >> 5, c4 = idx & 31;
    float4 v = *(const float4*)(src + row * D_DIM + c4 * 4);
    *(float4*)&sw[row][c4 * 4] = v;
  }
  __syncthreads();
#pragma unroll
  for (int e = 0; e < 2; ++e) {
    int f = t * 2 + e;
    int ct = f >> 6, l = f & 63;
    int kr = (l >> 4) * 8, col = ct * 16 + (l & 15);
    uint4 o;
    o.x = f2bf(sw[kr + 0][col]) | (f2bf(sw[kr + 1][col]) << 16);
    o.y = f2bf(sw[kr + 2][col]) | (f2bf(sw[kr + 3][col]) << 16);
    o.z = f2bf(sw[kr + 4][col]) | (f2bf(sw[kr + 5][col]) << 16);
    o.w = f2bf(sw[kr + 6][col]) | (f2bf(sw[kr + 7][col]) << 16);
    *(uint4*)(Bp + (((size_t)(ks * 8 + ct) << 6) + l) * 8) = o;
  }
}

// ---- Kernel 2: shared-tile GEMM, all streams via global_load_lds, counted vmcnt ----
// 256 blocks x 512 thr (8 waves). Block = 32 rows x 128 cols, K = 32 chunks of 64.
// Ring slot (24KB) = A(32x64 f32, src-XOR-swizzled) + B(16KB fragment-packed).
// 24 gll16/chunk (3 per wave), depth-4 ring, vmcnt(6) + raw s_barrier per chunk.
// Wave (rg=wv>>2, wc=wv&3) computes rows rg*16..+16, cols wc*32..+32; acc = 8 VGPRs.
#define CHK 64
#define NCHK (K_DIM / CHK)  // 32
#define SLOT 24576

__global__ __launch_bounds__(512, 2) void k_gemm(const float* __restrict__ X,
                                                 const unsigned short* __restrict__ Bp,
                                                 const float* __restrict__ bias,
                                                 unsigned short* __restrict__ Pn) {
  __shared__ __align__(16) unsigned char ring[4 * SLOT + 16384];  // 112 KB (ring + Pq)
  const int tid = threadIdx.x;
  const int lane = tid & 63;
  const int wv = tid >> 6;
  const int r0 = blockIdx.x * 32;
  const int l15 = lane & 15;
  const int kg = lane >> 4;
  const int rg = wv >> 2;
  const int wc = wv & 3;

  f32x4 acc[2];
  acc[0] = (f32x4){0.f, 0.f, 0.f, 0.f};
  acc[1] = (f32x4){0.f, 0.f, 0.f, 0.f};

  // stage chunk cc into ring slot cc&3: this wave issues instrs wv*3 .. wv*3+2 of 24
  auto stage = [&](int cc) {
    unsigned char* base = ring + (cc & 3) * SLOT;
#pragma unroll
    for (int u = 0; u < 3; ++u) {
      int i = wv * 3 + u;
      if (i < 8) {  // A: instr i = rows 4i..4i+3, 1KB contiguous dest
        int row = i * 4 + (lane >> 4);
        int gs = (lane & 15) ^ (row & 15);  // source pre-swizzle granule
        gll16(X + (size_t)(r0 + row) * K_DIM + cc * CHK + gs * 4, base + i * 1024);
      } else {      // B: instr j = fragment region (ksg = cc*2 + (j>>3), ct = j&7)
        int j = i - 8;
        int ksg = cc * 2 + (j >> 3);
        gll16(Bp + (((size_t)(ksg * 8 + (j & 7))) * 64 + lane) * 8, base + 8192 + j * 1024);
      }
    }
  };

  stage(0);
  stage(1);
  for (int c = 0; c < NCHK; ++c) {
    if (c + 2 < NCHK) {
      stage(c + 2);
      asm volatile("s_waitcnt vmcnt(6)" ::: "memory");   // chunk c landed (own 3)
    } else if (c + 1 < NCHK) {
      asm volatile("s_waitcnt vmcnt(3)" ::: "memory");
    } else {
      asm volatile("s_waitcnt vmcnt(0)" ::: "memory");
    }
    __builtin_amdgcn_s_barrier();                        // all waves' chunk-c loads visible
    const unsigned char* Ab = ring + (c & 3) * SLOT;
    const unsigned char* Bb = Ab + 8192;
#pragma unroll
    for (int s = 0; s < 2; ++s) {
      int row = rg * 16 + l15;
      int g = kg * 2 + s * 8;
      float4 alo = *(const float4*)(Ab + row * 256 + ((g ^ (row & 15)) << 4));
      float4 ahi = *(const float4*)(Ab + row * 256 + (((g + 1) ^ (row & 15)) << 4));
      short8 af = pack8(alo, ahi);
      short8 w0 = *(const short8*)(Bb + ((s * 8 + wc * 2 + 0) * 64 + lane) * 16);
      short8 w1 = *(const short8*)(Bb + ((s * 8 + wc * 2 + 1) * 64 + lane) * 16);
      acc[0] = __builtin_amdgcn_mfma_f32_16x16x32_bf16(w0, af, acc[0], 0, 0, 0);
      acc[1] = __builtin_amdgcn_mfma_f32_16x16x32_bf16(w1, af, acc[1], 0, 0, 0);
    }
  }

  // epilogue: acc -> Pq (16 KB, XOR-swizzled), then bias + row-norm + bf16 store
  unsigned char* Pq = ring + 4 * SLOT;
  {
    int row = rg * 16 + l15;
#pragma unroll
    for (int ctl = 0; ctl < 2; ++ctl) {
      int gq = (wc * 2 + ctl) * 4 + kg;  // col granule 0..31
      int byte = row * 512 + ((gq * 16) ^ ((row & 7) << 4));
      *(float4*)(Pq + byte) = make_float4(acc[ctl][0], acc[ctl][1], acc[ctl][2], acc[ctl][3]);
    }
  }
  __syncthreads();

  const int row = tid >> 4;  // 0..31
  const int c8 = tid & 15;   // 8 cols each
  float4 v0 = *(const float4*)(Pq + row * 512 + (((2 * c8) * 16) ^ ((row & 7) << 4)));
  float4 v1 = *(const float4*)(Pq + row * 512 + (((2 * c8 + 1) * 16) ^ ((row & 7) << 4)));
  float4 bv0 = *(const float4*)(bias + c8 * 8);
  float4 bv1 = *(const float4*)(bias + c8 * 8 + 4);
  float tot[8] = {v0.x + bv0.x, v0.y + bv0.y, v0.z + bv0.z, v0.w + bv0.w,
                  v1.x + bv1.x, v1.y + bv1.y, v1.z + bv1.z, v1.w + bv1.w};
  float ss = 0.f;
#pragma unroll
  for (int i = 0; i < 8; ++i) ss += tot[i] * tot[i];
  ss += __shfl_xor(ss, 1);
  ss += __shfl_xor(ss, 2);
  ss += __shfl_xor(ss, 4);
  ss += __shfl_xor(ss, 8);
  float sc = 1.0f / fmaxf(sqrtf(ss), 1e-12f);
  uint4 o;
  o.x = f2bf(tot[0] * sc) | (f2bf(tot[1] * sc) << 16);
  o.y = f2bf(tot[2] * sc) | (f2bf(tot[3] * sc) << 16);
  o.z = f2bf(tot[4] * sc) | (f2bf(tot[5] * sc) << 16);
  o.w = f2bf(tot[6] * sc) | (f2bf(tot[7] * sc) << 16);
  *(uint4*)(Pn + (size_t)(r0 + row) * D_DIM + c8 * 8) = o;
}

// ---------------- Kernel 3: banded similarity via MFMA ----------------
#define SROWS 144

__global__ __launch_bounds__(256) void k_sim(const unsigned short* __restrict__ Pn,
                                             float* __restrict__ out) {
  __shared__ unsigned short sm[SROWS * D_DIM];  // 36 KiB, XOR-swizzled 8-short groups
  const int bb = blockIdx.x >> 6;
  const int tb = blockIdx.x & 63;
  const int t0 = tb * 32;
  const int tid = threadIdx.x;

  for (int idx = tid; idx < SROWS * 16; idx += 256) {
    int i = idx >> 4, seg = idx & 15;
    int t = t0 - HWIN + i;
    uint4 val = make_uint4(0u, 0u, 0u, 0u);
    if (t >= 0 && t < T_LEN)
      val = *(const uint4*)(Pn + ((size_t)bb * T_LEN + t) * D_DIM + seg * 8);
    *(uint4*)&sm[i * D_DIM + ((seg ^ (i & 7)) << 3)] = val;
  }
  __syncthreads();

  const int lane = tid & 63;
  const int wv = tid >> 6;
  const int l15 = lane & 15;
  const int kg = lane >> 4;
  const int rt = wv >> 1;
  const int itp = wv & 1;

  short8 af[4];
  const int ia = HWIN + rt * 16 + l15;
#pragma unroll
  for (int ks = 0; ks < 4; ++ks) {
    int g = ks * 4 + kg;
    af[ks] = *(const short8*)&sm[ia * D_DIM + ((g ^ (ia & 7)) << 3)];
  }

  for (int it = itp; it < 9; it += 2) {
    f32x4 acc = (f32x4){0.f, 0.f, 0.f, 0.f};
    const int ib = it * 16 + l15;
#pragma unroll
    for (int ks = 0; ks < 4; ++ks) {
      int g = ks * 4 + kg;
      short8 bf = *(const short8*)&sm[ib * D_DIM + ((g ^ (ib & 7)) << 3)];
      acc = __builtin_amdgcn_mfma_f32_16x16x32_bf16(af[ks], bf, acc, 0, 0, 0);
    }
#pragma unroll
    for (int j = 0; j < 4; ++j) {
      int r = rt * 16 + kg * 4 + j;
      int w = ib - r;
      if (w >= 0 && w <= 100)
        out[((size_t)bb * T_LEN + t0 + r) * LOOKUP + w] = acc[j];
    }
  }
}

extern "C" void kernel_launch(void* const* d_in, const int* in_sizes, int n_in,
                              void* d_out, int out_size, void* d_ws, size_t ws_size,
                              hipStream_t stream) {
  (void)in_sizes; (void)n_in; (void)out_size; (void)ws_size;
  const float* x = (const float*)d_in[0];
  const float* W = (const float*)d_in[1];
  const float* b = (const float*)d_in[2];
  float* out = (float*)d_out;
  unsigned short* Bp = (unsigned short*)d_ws;            // 512 KiB fragment-packed W
  unsigned short* Pn = Bp + (size_t)D_DIM * K_DIM;       // 8192*128 bf16 = 2 MiB

  k_pack<<<64, 256, 0, stream>>>(W, Bp);
  k_gemm<<<M_DIM / 32, 512, 0, stream>>>(x, Bp, b, Pn);
  k_sim<<<4 * (T_LEN / 32), 256, 0, stream>>>(Pn, out);
}

// Round 11
// 34.614 us; speedup vs baseline: 2.3551x; 1.1570x over previous
//
#include <hip/hip_runtime.h>
#include <hip/hip_bf16.h>

#define T_LEN 2048
#define D_DIM 128
#define K_DIM 2048
#define M_DIM 8192
#define LOOKUP 101
#define HWIN 50

typedef __attribute__((ext_vector_type(8))) short short8;
typedef __attribute__((ext_vector_type(4))) float f32x4;

static __device__ __forceinline__ unsigned int f2bf(float f) {
  unsigned int u = __float_as_uint(f);
  return (u + 0x7fffu + ((u >> 16) & 1u)) >> 16;  // RNE bf16 bits
}

static __device__ __forceinline__ short8 pack8(float4 lo, float4 hi) {
  uint4 u;
  u.x = f2bf(lo.x) | (f2bf(lo.y) << 16);
  u.y = f2bf(lo.z) | (f2bf(lo.w) << 16);
  u.z = f2bf(hi.x) | (f2bf(hi.y) << 16);
  u.w = f2bf(hi.z) | (f2bf(hi.w) << 16);
  return *(short8*)&u;
}

typedef __attribute__((address_space(3))) unsigned char lds_uchar;
typedef const __attribute__((address_space(1))) unsigned char g_uchar;
static __device__ __forceinline__ void gll16(const void* g, void* l) {
  __builtin_amdgcn_global_load_lds((g_uchar*)g, (lds_uchar*)l, 16, 0, 0);
}

// ---- Kernel 1: W [2048][128] f32 -> Bp fragment-packed bf16 (512 KB) ----
// Bp granule (ksg, ct, lane) 16B = bf16 of W[ksg*32 + (lane>>4)*8 + j][ct*16 + (lane&15)], j=0..7
__global__ __launch_bounds__(256) void k_pack(const float* __restrict__ W,
                                              unsigned short* __restrict__ Bp) {
  __shared__ float sw[32][132];
  const int ks = blockIdx.x;  // 0..63
  const int t = threadIdx.x;
  const float* src = W + (size_t)ks * 32 * D_DIM;
#pragma unroll
  for (int j = 0; j < 4; ++j) {
    int idx = t + j * 256;
    int row = idx >> 5, c4 = idx & 31;
    float4 v = *(const float4*)(src + row * D_DIM + c4 * 4);
    *(float4*)&sw[row][c4 * 4] = v;
  }
  __syncthreads();
#pragma unroll
  for (int e = 0; e < 2; ++e) {
    int f = t * 2 + e;
    int ct = f >> 6, l = f & 63;
    int kr = (l >> 4) * 8, col = ct * 16 + (l & 15);
    uint4 o;
    o.x = f2bf(sw[kr + 0][col]) | (f2bf(sw[kr + 1][col]) << 16);
    o.y = f2bf(sw[kr + 2][col]) | (f2bf(sw[kr + 3][col]) << 16);
    o.z = f2bf(sw[kr + 4][col]) | (f2bf(sw[kr + 5][col]) << 16);
    o.w = f2bf(sw[kr + 6][col]) | (f2bf(sw[kr + 7][col]) << 16);
    *(uint4*)(Bp + (((size_t)(ks * 8 + ct) << 6) + l) * 8) = o;
  }
}

// ---- Kernel 2: T3/T4/T5 GEMM. 512 blocks x 256 thr (4 waves), 16 rows x 128 cols ----
// K = 16 chunks of 128. A: 2 gll16/wave/chunk -> 4-slot x 8KB ring (2 chunks ahead).
// B: direct-to-register, 8 contiguous 1KB loads/chunk, 1 chunk ahead, double-buffered.
// Steady vmcnt(12) (= A(c+1)2 + B(c+1)8 + A(c+2)2 newer than B(c)); tail 10 then 0.
// One s_barrier per chunk; setprio(1) around MFMA cluster. LDS 40KB -> 2 blocks/CU.
#define CHK 128
#define NCHK (K_DIM / CHK)  // 16

__global__ __launch_bounds__(256, 2) void k_gemm(const float* __restrict__ X,
                                                 const unsigned short* __restrict__ Bp,
                                                 const float* __restrict__ bias,
                                                 unsigned short* __restrict__ Pn) {
  __shared__ __align__(16) unsigned char ring[4 * 8192 + 8192];  // ring 32KB + Pq 8KB
  const int tid = threadIdx.x;
  const int lane = tid & 63;
  const int wv = tid >> 6;    // 0..3 = col-pair
  const int r0 = blockIdx.x * 16;
  const int l15 = lane & 15;
  const int kg = lane >> 4;
  const int wc = wv;

  f32x4 acc[2];
  acc[0] = (f32x4){0.f, 0.f, 0.f, 0.f};
  acc[1] = (f32x4){0.f, 0.f, 0.f, 0.f};

  // stage chunk cc (16 rows x 512B = 8KB) into slot cc&3; this wave: 2 instrs of 1KB (2 rows each)
  auto stage = [&](int cc) {
    unsigned char* base = ring + (cc & 3) * 8192;
#pragma unroll
    for (int u = 0; u < 2; ++u) {
      int idx = wv * 2 + u;                 // 0..7
      int row = idx * 2 + (lane >> 5);      // 0..15
      int gs = (lane & 31) ^ (row & 7);     // source pre-swizzle granule (16B units)
      gll16(X + (size_t)(r0 + row) * K_DIM + cc * CHK + gs * 4, base + idx * 1024);
    }
  };
  // B fragments for chunk cc: P[s*2+t] = frag(ksg = cc*4+s, ct = wc*2+t)
#define LOADB(P, cc)                                                                     \
  {                                                                                      \
    _Pragma("unroll") for (int q = 0; q < 4; ++q) {                                      \
      _Pragma("unroll") for (int t = 0; t < 2; ++t)                                      \
          P[q * 2 + t] = *(const short8*)(Bp +                                           \
              (((size_t)((cc) * 4 + q) * 8 + (wc * 2 + t)) * 64 + lane) * 8);            \
    }                                                                                    \
  }

  short8 breg[2][8];

  // prologue order: A(0), B(0), A(1)  -> uniform steady-state vmcnt(12)
  stage(0);
  LOADB(breg[0], 0);
  stage(1);

#pragma unroll
  for (int c = 0; c < NCHK; ++c) {
    if (c + 1 < NCHK) LOADB(breg[(c + 1) & 1], c + 1);
    if (c + 2 < NCHK) stage(c + 2);
    if (c <= NCHK - 3) {
      asm volatile("s_waitcnt vmcnt(12)" ::: "memory");
    } else if (c == NCHK - 2) {
      asm volatile("s_waitcnt vmcnt(10)" ::: "memory");
    } else {
      asm volatile("s_waitcnt vmcnt(0)" ::: "memory");
    }
    __builtin_amdgcn_s_barrier();
    const unsigned char* Ab = ring + (c & 3) * 8192;
    __builtin_amdgcn_s_setprio(1);
#pragma unroll
    for (int s = 0; s < 4; ++s) {
      int g0 = s * 8 + kg * 2;
      float4 alo = *(const float4*)(Ab + l15 * 512 + ((g0 ^ (l15 & 7)) << 4));
      float4 ahi = *(const float4*)(Ab + l15 * 512 + (((g0 + 1) ^ (l15 & 7)) << 4));
      short8 af = pack8(alo, ahi);
      acc[0] = __builtin_amdgcn_mfma_f32_16x16x32_bf16(breg[c & 1][s * 2 + 0], af, acc[0], 0, 0, 0);
      acc[1] = __builtin_amdgcn_mfma_f32_16x16x32_bf16(breg[c & 1][s * 2 + 1], af, acc[1], 0, 0, 0);
    }
    __builtin_amdgcn_s_setprio(0);
  }

  // epilogue: acc -> Pq (8KB, XOR-swizzled), bias + row-norm + bf16 store
  // acc[ctl][j] = p[row = l15][col = (wc*2+ctl)*16 + kg*4 + j]
  unsigned char* Pq = ring + 4 * 8192;
#pragma unroll
  for (int ctl = 0; ctl < 2; ++ctl) {
    int gq = (wc * 2 + ctl) * 4 + kg;  // col granule 0..31
    int byte = l15 * 512 + ((gq << 4) ^ ((l15 & 7) << 4));
    *(float4*)(Pq + byte) = make_float4(acc[ctl][0], acc[ctl][1], acc[ctl][2], acc[ctl][3]);
  }
  __syncthreads();

  const int row = tid >> 4;  // 0..15
  const int c8 = tid & 15;   // 8 cols each
  float4 v0 = *(const float4*)(Pq + row * 512 + (((2 * c8) << 4) ^ ((row & 7) << 4)));
  float4 v1 = *(const float4*)(Pq + row * 512 + (((2 * c8 + 1) << 4) ^ ((row & 7) << 4)));
  float4 bv0 = *(const float4*)(bias + c8 * 8);
  float4 bv1 = *(const float4*)(bias + c8 * 8 + 4);
  float tot[8] = {v0.x + bv0.x, v0.y + bv0.y, v0.z + bv0.z, v0.w + bv0.w,
                  v1.x + bv1.x, v1.y + bv1.y, v1.z + bv1.z, v1.w + bv1.w};
  float ss = 0.f;
#pragma unroll
  for (int i = 0; i < 8; ++i) ss += tot[i] * tot[i];
  ss += __shfl_xor(ss, 1);
  ss += __shfl_xor(ss, 2);
  ss += __shfl_xor(ss, 4);
  ss += __shfl_xor(ss, 8);
  float sc = 1.0f / fmaxf(sqrtf(ss), 1e-12f);
  uint4 o;
  o.x = f2bf(tot[0] * sc) | (f2bf(tot[1] * sc) << 16);
  o.y = f2bf(tot[2] * sc) | (f2bf(tot[3] * sc) << 16);
  o.z = f2bf(tot[4] * sc) | (f2bf(tot[5] * sc) << 16);
  o.w = f2bf(tot[6] * sc) | (f2bf(tot[7] * sc) << 16);
  *(uint4*)(Pn + (size_t)(r0 + row) * D_DIM + c8 * 8) = o;
}

// ---------------- Kernel 3: banded similarity via MFMA ----------------
#define SROWS 144

__global__ __launch_bounds__(256) void k_sim(const unsigned short* __restrict__ Pn,
                                             float* __restrict__ out) {
  __shared__ unsigned short sm[SROWS * D_DIM];  // 36 KiB, XOR-swizzled 8-short groups
  const int bb = blockIdx.x >> 6;
  const int tb = blockIdx.x & 63;
  const int t0 = tb * 32;
  const int tid = threadIdx.x;

  for (int idx = tid; idx < SROWS * 16; idx += 256) {
    int i = idx >> 4, seg = idx & 15;
    int t = t0 - HWIN + i;
    uint4 val = make_uint4(0u, 0u, 0u, 0u);
    if (t >= 0 && t < T_LEN)
      val = *(const uint4*)(Pn + ((size_t)bb * T_LEN + t) * D_DIM + seg * 8);
    *(uint4*)&sm[i * D_DIM + ((seg ^ (i & 7)) << 3)] = val;
  }
  __syncthreads();

  const int lane = tid & 63;
  const int wv = tid >> 6;
  const int l15 = lane & 15;
  const int kg = lane >> 4;
  const int rt = wv >> 1;
  const int itp = wv & 1;

  short8 af[4];
  const int ia = HWIN + rt * 16 + l15;
#pragma unroll
  for (int ks = 0; ks < 4; ++ks) {
    int g = ks * 4 + kg;
    af[ks] = *(const short8*)&sm[ia * D_DIM + ((g ^ (ia & 7)) << 3)];
  }

  for (int it = itp; it < 9; it += 2) {
    f32x4 acc = (f32x4){0.f, 0.f, 0.f, 0.f};
    const int ib = it * 16 + l15;
#pragma unroll
    for (int ks = 0; ks < 4; ++ks) {
      int g = ks * 4 + kg;
      short8 bf = *(const short8*)&sm[ib * D_DIM + ((g ^ (ib & 7)) << 3)];
      acc = __builtin_amdgcn_mfma_f32_16x16x32_bf16(af[ks], bf, acc, 0, 0, 0);
    }
#pragma unroll
    for (int j = 0; j < 4; ++j) {
      int r = rt * 16 + kg * 4 + j;
      int w = ib - r;
      if (w >= 0 && w <= 100)
        out[((size_t)bb * T_LEN + t0 + r) * LOOKUP + w] = acc[j];
    }
  }
}

extern "C" void kernel_launch(void* const* d_in, const int* in_sizes, int n_in,
                              void* d_out, int out_size, void* d_ws, size_t ws_size,
                              hipStream_t stream) {
  (void)in_sizes; (void)n_in; (void)out_size; (void)ws_size;
  const float* x = (const float*)d_in[0];
  const float* W = (const float*)d_in[1];
  const float* b = (const float*)d_in[2];
  float* out = (float*)d_out;
  unsigned short* Bp = (unsigned short*)d_ws;            // 512 KiB fragment-packed W
  unsigned short* Pn = Bp + (size_t)D_DIM * K_DIM;       // 8192*128 bf16 = 2 MiB

  k_pack<<<64, 256, 0, stream>>>(W, Bp);
  k_gemm<<<M_DIM / 16, 256, 0, stream>>>(x, Bp, b, Pn);
  k_sim<<<4 * (T_LEN / 32), 256, 0, stream>>>(Pn, out);
}